// Round 1
// baseline (194.437 us; speedup 1.0000x reference)
//
#include <hip/hip_runtime.h>

#define BS 16
#define NNODES 20000
#define CIN 32
#define SEQ 9
#define COUT 64
#define KTOT 288
#define MPOOL 5000
#define NNZ 20000

#define NT 256      // nodes per block
#define GPAD 40     // g_lds row stride (bf16 elems): 80B = 20 dwords -> uniform 2-way banks
#define WPAD 296    // w_lds row stride (bf16 elems): 592B = 148 dwords -> uniform 2-way banks

typedef __attribute__((ext_vector_type(8))) short bf16x8;
typedef __attribute__((ext_vector_type(4))) float f32x4;

static __device__ __forceinline__ unsigned short f2bf(float f) {
  unsigned u = __float_as_uint(f);
  u += 0x7FFF + ((u >> 16) & 1);   // RNE
  return (unsigned short)(u >> 16);
}
static __device__ __forceinline__ float bf2f(unsigned short s) {
  return __uint_as_float(((unsigned)s) << 16);
}

__global__ __launch_bounds__(256, 2) void gemm_elu_kernel(
    const float* __restrict__ x,        // [BS][NNODES][CIN]
    const int* __restrict__ indices,    // [NNODES][SEQ]
    const float* __restrict__ weight,   // [COUT][KTOT]
    const float* __restrict__ bias,     // [COUT]
    unsigned short* __restrict__ h)     // [BS][NNODES][COUT] bf16
{
  __shared__ unsigned short w_lds[COUT * WPAD];
  __shared__ unsigned short g_lds[NT * GPAD];
  __shared__ int idx_lds[NT * SEQ];

  const int b = blockIdx.y;
  const int n0 = blockIdx.x * NT;
  const int tid = threadIdx.x;

  // ---- stage weight (64x288 f32 -> bf16), one-time ----
  for (int i = tid; i < COUT * (KTOT / 4); i += 256) {
    const float4 wv = ((const float4*)weight)[i];
    const int o = i / (KTOT / 4);
    const int k4 = (i % (KTOT / 4)) * 4;
    unsigned p0 = (unsigned)f2bf(wv.x) | ((unsigned)f2bf(wv.y) << 16);
    unsigned p1 = (unsigned)f2bf(wv.z) | ((unsigned)f2bf(wv.w) << 16);
    *(uint2*)&w_lds[o * WPAD + k4] = make_uint2(p0, p1);
  }

  // ---- stage spiral indices for this node tile (coalesced) ----
  for (int i = tid; i < NT * SEQ; i += 256) {
    const int gidx = n0 * SEQ + i;
    idx_lds[i] = (gidx < NNODES * SEQ) ? indices[gidx] : 0;
  }
  __syncthreads();

  f32x4 acc[4][4];
#pragma unroll
  for (int a = 0; a < 4; ++a)
#pragma unroll
    for (int o = 0; o < 4; ++o) {
      f32x4 z = {0.f, 0.f, 0.f, 0.f};
      acc[a][o] = z;
    }

  const int wv = tid >> 6;
  const int lane = tid & 63;
  const int l16 = lane & 15;
  const int lhi = lane >> 4;
  const float* __restrict__ xb = x + (size_t)b * NNODES * CIN;

  for (int kk = 0; kk < SEQ; ++kk) {
    // ---- stage gathered chunk: 256 rows x 32 ch (spiral element kk) ----
    // 16 threads per row, each loads float2 (row = 128B coalesced), writes bf16x2
#pragma unroll
    for (int p = 0; p < 16; ++p) {
      const int row = p * 16 + (tid >> 4);
      const int c2 = tid & 15;
      const int gi = idx_lds[row * SEQ + kk];
      const float2 v = ((const float2*)(xb + (size_t)gi * CIN))[c2];
      *(unsigned*)&g_lds[row * GPAD + c2 * 2] =
          (unsigned)f2bf(v.x) | ((unsigned)f2bf(v.y) << 16);
    }
    __syncthreads();

    // ---- fragments + MFMA: wave wv owns nodes [wv*64, wv*64+64) x all 64 out ----
    bf16x8 af[4], bfr[4];
#pragma unroll
    for (int i = 0; i < 4; ++i) {
      af[i]  = *(const bf16x8*)&g_lds[(wv * 64 + i * 16 + l16) * GPAD + lhi * 8];
      bfr[i] = *(const bf16x8*)&w_lds[(i * 16 + l16) * WPAD + kk * 32 + lhi * 8];
    }
#pragma unroll
    for (int a = 0; a < 4; ++a)
#pragma unroll
      for (int o = 0; o < 4; ++o)
        acc[a][o] = __builtin_amdgcn_mfma_f32_16x16x32_bf16(af[a], bfr[o], acc[a][o], 0, 0, 0);
    __syncthreads();
  }

  // ---- epilogue: bias + elu, write h as bf16 ----
  // D layout (m89): col(=out) = lane&15, row(=node) = (lane>>4)*4 + reg
#pragma unroll
  for (int o = 0; o < 4; ++o) {
    const int oc = o * 16 + l16;
    const float bv = bias[oc];
#pragma unroll
    for (int a = 0; a < 4; ++a) {
#pragma unroll
      for (int r = 0; r < 4; ++r) {
        const int node = n0 + wv * 64 + a * 16 + lhi * 4 + r;
        if (node < NNODES) {
          float vvv = acc[a][o][r] + bv;
          vvv = vvv > 0.f ? vvv : expm1f(vvv);
          h[((size_t)b * NNODES + node) * COUT + oc] = f2bf(vvv);
        }
      }
    }
  }
}

__global__ __launch_bounds__(256) void scatter_kernel(
    const unsigned short* __restrict__ h,   // [BS][NNODES][COUT] bf16
    const int* __restrict__ rows,
    const int* __restrict__ cols,
    const float* __restrict__ vals,
    float* __restrict__ out)                // [BS][MPOOL][COUT]
{
  const int gw = (int)((blockIdx.x * blockDim.x + threadIdx.x) >> 6);
  const int lane = threadIdx.x & 63;
  const int nw = (int)((gridDim.x * blockDim.x) >> 6);
  for (int t = gw; t < NNZ * BS; t += nw) {
    const int k = t >> 4;     // nnz index
    const int b = t & 15;     // batch
    const int r = rows[k];
    const int c = cols[k];
    const float v = vals[k];
    const float hv = bf2f(h[((size_t)b * NNODES + c) * COUT + lane]);
    atomicAdd(&out[((size_t)b * MPOOL + r) * COUT + lane], hv * v);
  }
}

extern "C" void kernel_launch(void* const* d_in, const int* in_sizes, int n_in,
                              void* d_out, int out_size, void* d_ws, size_t ws_size,
                              hipStream_t stream) {
  const float* x       = (const float*)d_in[0];
  const int*   indices = (const int*)d_in[1];
  const float* weight  = (const float*)d_in[2];
  const float* bias    = (const float*)d_in[3];
  const int*   trows   = (const int*)d_in[4];
  const int*   tcols   = (const int*)d_in[5];
  const float* tvals   = (const float*)d_in[6];
  float* out = (float*)d_out;
  unsigned short* h = (unsigned short*)d_ws;   // 16*20000*64 bf16 = 40.96 MB

  hipMemsetAsync(d_out, 0, (size_t)out_size * sizeof(float), stream);

  dim3 gridA((NNODES + NT - 1) / NT, BS);
  gemm_elu_kernel<<<gridA, 256, 0, stream>>>(x, indices, weight, bias, h);

  scatter_kernel<<<2048, 256, 0, stream>>>(h, trows, tcols, tvals, out);
}

// Round 2
// 168.343 us; speedup vs baseline: 1.1550x; 1.1550x over previous
//
#include <hip/hip_runtime.h>

#define BS 16
#define NNODES 20000
#define CIN 32
#define SEQ 9
#define COUT 64
#define KTOT 288
#define MPOOL 5000
#define NNZ 20000

#define NT 256      // nodes per block (4 waves x 64 nodes)
#define WPAD 296    // w_lds row stride (bf16): 592B = 148 dwords -> 2-way banks (free)

#define H_BYTES  40960000ULL   // 16*20000*64 * 2
#define XB_BYTES 20480000ULL   // 16*20000*32 * 2

typedef __attribute__((ext_vector_type(8))) short bf16x8;
typedef __attribute__((ext_vector_type(4))) float f32x4;

static __device__ __forceinline__ unsigned short f2bf(float f) {
  unsigned u = __float_as_uint(f);
  u += 0x7FFF + ((u >> 16) & 1);   // RNE
  return (unsigned short)(u >> 16);
}
static __device__ __forceinline__ float bf2f(unsigned short s) {
  return __uint_as_float(((unsigned)s) << 16);
}

// ---- pre-pass: x f32 -> bf16 (10.24M elems, 8 per thread) ----
__global__ __launch_bounds__(256) void cvt_kernel(const float* __restrict__ x,
                                                  unsigned short* __restrict__ xb) {
  const size_t base = ((size_t)blockIdx.x * 256 + threadIdx.x) * 8;
  const float4 v0 = *(const float4*)(x + base);
  const float4 v1 = *(const float4*)(x + base + 4);
  uint4 p;
  p.x = (unsigned)f2bf(v0.x) | ((unsigned)f2bf(v0.y) << 16);
  p.y = (unsigned)f2bf(v0.z) | ((unsigned)f2bf(v0.w) << 16);
  p.z = (unsigned)f2bf(v1.x) | ((unsigned)f2bf(v1.y) << 16);
  p.w = (unsigned)f2bf(v1.z) | ((unsigned)f2bf(v1.w) << 16);
  *(uint4*)(xb + base) = p;
}

// ---- gemm+elu: barrier-free K loop, A-fragments gathered straight from global ----
template <int XBF>
__global__ __launch_bounds__(256) void gemm_elu_kernel(
    const float* __restrict__ x,            // [BS][NNODES][CIN] f32
    const unsigned short* __restrict__ xb,  // [BS][NNODES][CIN] bf16 (if XBF)
    const int* __restrict__ indices,        // [NNODES][SEQ]
    const float* __restrict__ weight,       // [COUT][KTOT]
    const float* __restrict__ bias,         // [COUT]
    unsigned short* __restrict__ h)         // [BS][NNODES][COUT] bf16
{
  __shared__ unsigned short w_lds[COUT * WPAD];
  __shared__ int idx_lds[NT * SEQ];

  const int b = blockIdx.y;
  const int n0 = blockIdx.x * NT;
  const int tid = threadIdx.x;

  // stage weight (64x288 f32 -> bf16)
  for (int i = tid; i < COUT * (KTOT / 4); i += 256) {
    const float4 wv = ((const float4*)weight)[i];
    const int o = i / (KTOT / 4);
    const int k4 = (i % (KTOT / 4)) * 4;
    unsigned p0 = (unsigned)f2bf(wv.x) | ((unsigned)f2bf(wv.y) << 16);
    unsigned p1 = (unsigned)f2bf(wv.z) | ((unsigned)f2bf(wv.w) << 16);
    *(uint2*)&w_lds[o * WPAD + k4] = make_uint2(p0, p1);
  }
  // stage spiral indices (coalesced)
  for (int i = tid; i < NT * SEQ; i += 256) {
    const int gidx = n0 * SEQ + i;
    idx_lds[i] = (gidx < NNODES * SEQ) ? indices[gidx] : 0;
  }
  __syncthreads();

  const int wv = tid >> 6;
  const int lane = tid & 63;
  const int l16 = lane & 15;
  const int lhi = lane >> 4;

  f32x4 acc[4][4];
#pragma unroll
  for (int a = 0; a < 4; ++a)
#pragma unroll
    for (int o = 0; o < 4; ++o) {
      f32x4 z = {0.f, 0.f, 0.f, 0.f};
      acc[a][o] = z;
    }

#pragma unroll
  for (int kk = 0; kk < SEQ; ++kk) {
    bf16x8 af[4], bfr[4];
#pragma unroll
    for (int i = 0; i < 4; ++i) {
      const int node = wv * 64 + i * 16 + l16;
      const int gi = idx_lds[node * SEQ + kk];
      if (XBF) {
        af[i] = *(const bf16x8*)&xb[((size_t)b * NNODES + gi) * CIN + lhi * 8];
      } else {
        const float* xr = x + ((size_t)b * NNODES + gi) * CIN + lhi * 8;
        const float4 u0 = *(const float4*)xr;
        const float4 u1 = *(const float4*)(xr + 4);
        bf16x8 t;
        t[0] = (short)f2bf(u0.x); t[1] = (short)f2bf(u0.y);
        t[2] = (short)f2bf(u0.z); t[3] = (short)f2bf(u0.w);
        t[4] = (short)f2bf(u1.x); t[5] = (short)f2bf(u1.y);
        t[6] = (short)f2bf(u1.z); t[7] = (short)f2bf(u1.w);
        af[i] = t;
      }
      bfr[i] = *(const bf16x8*)&w_lds[(i * 16 + l16) * WPAD + kk * 32 + lhi * 8];
    }
#pragma unroll
    for (int a = 0; a < 4; ++a)
#pragma unroll
      for (int o = 0; o < 4; ++o)
        acc[a][o] = __builtin_amdgcn_mfma_f32_16x16x32_bf16(af[a], bfr[o], acc[a][o], 0, 0, 0);
  }

  // epilogue: bias + elu -> h bf16.  D layout: col=lane&15, row=(lane>>4)*4+reg
#pragma unroll
  for (int o = 0; o < 4; ++o) {
    const int oc = o * 16 + l16;
    const float bv = bias[oc];
#pragma unroll
    for (int a = 0; a < 4; ++a) {
#pragma unroll
      for (int r = 0; r < 4; ++r) {
        const int node = n0 + wv * 64 + a * 16 + lhi * 4 + r;
        if (node < NNODES) {
          float vvv = acc[a][o][r] + bv;
          vvv = vvv > 0.f ? vvv : expm1f(vvv);
          h[((size_t)b * NNODES + node) * COUT + oc] = f2bf(vvv);
        }
      }
    }
  }
}

__global__ __launch_bounds__(256) void scatter_kernel(
    const unsigned short* __restrict__ h,   // [BS][NNODES][COUT] bf16
    const int* __restrict__ rows,
    const int* __restrict__ cols,
    const float* __restrict__ vals,
    float* __restrict__ out)                // [BS][MPOOL][COUT]
{
  const int gw = (int)((blockIdx.x * blockDim.x + threadIdx.x) >> 6);
  const int lane = threadIdx.x & 63;
  const int nw = (int)((gridDim.x * blockDim.x) >> 6);
  for (int t = gw; t < NNZ * BS; t += nw) {
    const int k = t >> 4;     // nnz index
    const int b = t & 15;     // batch
    const int r = rows[k];
    const int c = cols[k];
    const float v = vals[k];
    const float hv = bf2f(h[((size_t)b * NNODES + c) * COUT + lane]);
    atomicAdd(&out[((size_t)b * MPOOL + r) * COUT + lane], hv * v);
  }
}

extern "C" void kernel_launch(void* const* d_in, const int* in_sizes, int n_in,
                              void* d_out, int out_size, void* d_ws, size_t ws_size,
                              hipStream_t stream) {
  const float* x       = (const float*)d_in[0];
  const int*   indices = (const int*)d_in[1];
  const float* weight  = (const float*)d_in[2];
  const float* bias    = (const float*)d_in[3];
  const int*   trows   = (const int*)d_in[4];
  const int*   tcols   = (const int*)d_in[5];
  const float* tvals   = (const float*)d_in[6];
  float* out = (float*)d_out;

  unsigned short* h  = (unsigned short*)d_ws;
  unsigned short* xb = (unsigned short*)((char*)d_ws + H_BYTES);
  const bool use_xb = (ws_size >= H_BYTES + XB_BYTES);

  hipMemsetAsync(d_out, 0, (size_t)out_size * sizeof(float), stream);

  dim3 gridA((NNODES + NT - 1) / NT, BS);
  if (use_xb) {
    cvt_kernel<<<(BS * NNODES * CIN) / (256 * 8), 256, 0, stream>>>(x, xb);
    gemm_elu_kernel<1><<<gridA, 256, 0, stream>>>(x, xb, indices, weight, bias, h);
  } else {
    gemm_elu_kernel<0><<<gridA, 256, 0, stream>>>(x, xb, indices, weight, bias, h);
  }

  scatter_kernel<<<4096, 256, 0, stream>>>(h, trows, tcols, tvals, out);
}

// Round 3
// 140.555 us; speedup vs baseline: 1.3833x; 1.1977x over previous
//
#include <hip/hip_runtime.h>

#define BS 16
#define NNODES 20000
#define CIN 32
#define SEQ 9
#define COUT 64
#define KTOT 288
#define MPOOL 5000
#define NNZ 20000

#define NT 256      // nodes per block (4 waves x 64 nodes)
#define WPAD 296    // w_lds row stride (bf16)

#define H_BYTES   40960000ULL   // 16*20000*64 * 2
#define XB_BYTES  20480000ULL   // 16*20000*32 * 2
// aux (CSR) region after h+xb: cnt[5000], cursor[5000], start[5001], csr[20000]
#define AUX_INTS  (5000 + 5000 + 5001 + NNZ)

typedef __attribute__((ext_vector_type(8))) short bf16x8;
typedef __attribute__((ext_vector_type(4))) float f32x4;

static __device__ __forceinline__ unsigned short f2bf(float f) {
  unsigned u = __float_as_uint(f);
  u += 0x7FFF + ((u >> 16) & 1);   // RNE
  return (unsigned short)(u >> 16);
}
static __device__ __forceinline__ float bf2f(unsigned short s) {
  return __uint_as_float(((unsigned)s) << 16);
}

// ---- pre-pass: x f32 -> bf16 ----
__global__ __launch_bounds__(256) void cvt_kernel(const float* __restrict__ x,
                                                  unsigned short* __restrict__ xb) {
  const size_t base = ((size_t)blockIdx.x * 256 + threadIdx.x) * 8;
  const float4 v0 = *(const float4*)(x + base);
  const float4 v1 = *(const float4*)(x + base + 4);
  uint4 p;
  p.x = (unsigned)f2bf(v0.x) | ((unsigned)f2bf(v0.y) << 16);
  p.y = (unsigned)f2bf(v0.z) | ((unsigned)f2bf(v0.w) << 16);
  p.z = (unsigned)f2bf(v1.x) | ((unsigned)f2bf(v1.y) << 16);
  p.w = (unsigned)f2bf(v1.z) | ((unsigned)f2bf(v1.w) << 16);
  *(uint4*)(xb + base) = p;
}

// ---- gemm+elu with XCD-affinity swizzle: each XCD owns 2 batches ----
__global__ __launch_bounds__(256, 3) void gemm_elu_kernel(
    const unsigned short* __restrict__ xb,  // [BS][NNODES][CIN] bf16
    const int* __restrict__ indices,        // [NNODES][SEQ]
    const float* __restrict__ weight,       // [COUT][KTOT]
    const float* __restrict__ bias,         // [COUT]
    unsigned short* __restrict__ h)         // [BS][NNODES][COUT] bf16
{
  __shared__ unsigned short w_lds[COUT * WPAD];
  __shared__ int idx_lds[NT * SEQ];

  // swizzle: id -> (xcd, slot); b = xcd*2 + (slot&1); tile = slot>>1
  const int id = blockIdx.x;
  const int xcd = id & 7;
  const int slot = id >> 3;
  const int b = xcd * 2 + (slot & 1);
  const int n0 = (slot >> 1) * NT;
  const int tid = threadIdx.x;

  for (int i = tid; i < COUT * (KTOT / 4); i += 256) {
    const float4 wv = ((const float4*)weight)[i];
    const int o = i / (KTOT / 4);
    const int k4 = (i % (KTOT / 4)) * 4;
    unsigned p0 = (unsigned)f2bf(wv.x) | ((unsigned)f2bf(wv.y) << 16);
    unsigned p1 = (unsigned)f2bf(wv.z) | ((unsigned)f2bf(wv.w) << 16);
    *(uint2*)&w_lds[o * WPAD + k4] = make_uint2(p0, p1);
  }
  for (int i = tid; i < NT * SEQ; i += 256) {
    const int gidx = n0 * SEQ + i;
    idx_lds[i] = (gidx < NNODES * SEQ) ? indices[gidx] : 0;
  }
  __syncthreads();

  const int wv = tid >> 6;
  const int lane = tid & 63;
  const int l16 = lane & 15;
  const int lhi = lane >> 4;

  f32x4 acc[4][4];
#pragma unroll
  for (int a = 0; a < 4; ++a)
#pragma unroll
    for (int o = 0; o < 4; ++o) {
      f32x4 z = {0.f, 0.f, 0.f, 0.f};
      acc[a][o] = z;
    }

#pragma unroll
  for (int kk = 0; kk < SEQ; ++kk) {
    bf16x8 af[4], bfr[4];
#pragma unroll
    for (int i = 0; i < 4; ++i) {
      const int node = wv * 64 + i * 16 + l16;
      const int gi = idx_lds[node * SEQ + kk];
      af[i]  = *(const bf16x8*)&xb[((size_t)b * NNODES + gi) * CIN + lhi * 8];
      bfr[i] = *(const bf16x8*)&w_lds[(i * 16 + l16) * WPAD + kk * 32 + lhi * 8];
    }
#pragma unroll
    for (int a = 0; a < 4; ++a)
#pragma unroll
      for (int o = 0; o < 4; ++o)
        acc[a][o] = __builtin_amdgcn_mfma_f32_16x16x32_bf16(af[a], bfr[o], acc[a][o], 0, 0, 0);
  }

  // epilogue: bias + elu -> h bf16.  D layout: col=lane&15, row=(lane>>4)*4+reg
#pragma unroll
  for (int o = 0; o < 4; ++o) {
    const int oc = o * 16 + l16;
    const float bv = bias[oc];
#pragma unroll
    for (int a = 0; a < 4; ++a) {
#pragma unroll
      for (int r = 0; r < 4; ++r) {
        const int node = n0 + wv * 64 + a * 16 + lhi * 4 + r;
        if (node < NNODES) {
          float vvv = acc[a][o][r] + bv;
          vvv = vvv > 0.f ? vvv : expm1f(vvv);
          h[((size_t)b * NNODES + node) * COUT + oc] = f2bf(vvv);
        }
      }
    }
  }
}

// ---- CSR build ----
__global__ __launch_bounds__(256) void hist_kernel(const int* __restrict__ rows,
                                                   int* __restrict__ cnt) {
  const int k = blockIdx.x * 256 + threadIdx.x;
  if (k < NNZ) atomicAdd(&cnt[rows[k]], 1);
}

__global__ __launch_bounds__(256) void scan_kernel(const int* __restrict__ cnt,
                                                   int* __restrict__ start) {
  __shared__ int part[256];
  const int t = threadIdx.x;
  const int base = t * 20;
  int local[20];
  int s = 0;
#pragma unroll
  for (int j = 0; j < 20; ++j) {
    const int i = base + j;
    local[j] = s;
    s += (i < MPOOL) ? cnt[i] : 0;
  }
  part[t] = s;
  __syncthreads();
  for (int off = 1; off < 256; off <<= 1) {
    const int v = (t >= off) ? part[t - off] : 0;
    __syncthreads();
    part[t] += v;
    __syncthreads();
  }
  const int excl = (t == 0) ? 0 : part[t - 1];
#pragma unroll
  for (int j = 0; j < 20; ++j) {
    const int i = base + j;
    if (i < MPOOL) start[i] = excl + local[j];
  }
  if (t == 255) start[MPOOL] = part[255];
}

__global__ __launch_bounds__(256) void reorder_kernel(const int* __restrict__ rows,
                                                      const int* __restrict__ start,
                                                      int* __restrict__ cursor,
                                                      int* __restrict__ csr) {
  const int k = blockIdx.x * 256 + threadIdx.x;
  if (k < NNZ) {
    const int r = rows[k];
    const int pos = atomicAdd(&cursor[r], 1);
    csr[start[r] + pos] = k;
  }
}

// ---- pool: one wave per (row, b), atomic-free, XCD b-affinity ----
__global__ __launch_bounds__(256) void pool_kernel(
    const unsigned short* __restrict__ h,   // [BS][NNODES][COUT] bf16
    const int* __restrict__ cols,
    const float* __restrict__ vals,
    const int* __restrict__ start,
    const int* __restrict__ csr,
    float* __restrict__ out)                // [BS][MPOOL][COUT]
{
  const int id = blockIdx.x;                // 20000 blocks
  const int xcd = id & 7;
  const int slot = id >> 3;                 // 0..2499
  const int b = xcd * 2 + (slot & 1);
  const int rg = slot >> 1;                 // 0..1249
  const int wv = (int)(threadIdx.x >> 6);
  const int lane = (int)(threadIdx.x & 63);
  const int r = rg * 4 + wv;

  const int s = start[r];
  const int e = start[r + 1];
  float acc = 0.f;
  for (int j = s; j < e; ++j) {
    const int k = csr[j];
    const int c = cols[k];
    const float v = vals[k];
    acc += v * bf2f(h[((size_t)b * NNODES + c) * COUT + lane]);
  }
  out[((size_t)b * MPOOL + r) * COUT + lane] = acc;
}

// ---- fallback atomic scatter (small ws) ----
__global__ __launch_bounds__(256) void scatter_kernel(
    const unsigned short* __restrict__ h,
    const int* __restrict__ rows,
    const int* __restrict__ cols,
    const float* __restrict__ vals,
    float* __restrict__ out)
{
  const int gw = (int)((blockIdx.x * blockDim.x + threadIdx.x) >> 6);
  const int lane = threadIdx.x & 63;
  const int nw = (int)((gridDim.x * blockDim.x) >> 6);
  for (int t = gw; t < NNZ * BS; t += nw) {
    const int k = t >> 4;
    const int b = t & 15;
    const float hv = bf2f(h[((size_t)b * NNODES + cols[k]) * COUT + lane]);
    atomicAdd(&out[((size_t)b * MPOOL + rows[k]) * COUT + lane], hv * vals[k]);
  }
}

extern "C" void kernel_launch(void* const* d_in, const int* in_sizes, int n_in,
                              void* d_out, int out_size, void* d_ws, size_t ws_size,
                              hipStream_t stream) {
  const float* x       = (const float*)d_in[0];
  const int*   indices = (const int*)d_in[1];
  const float* weight  = (const float*)d_in[2];
  const float* bias    = (const float*)d_in[3];
  const int*   trows   = (const int*)d_in[4];
  const int*   tcols   = (const int*)d_in[5];
  const float* tvals   = (const float*)d_in[6];
  float* out = (float*)d_out;

  unsigned short* h  = (unsigned short*)d_ws;
  unsigned short* xb = (unsigned short*)((char*)d_ws + H_BYTES);
  int* aux    = (int*)((char*)d_ws + H_BYTES + XB_BYTES);
  int* cnt    = aux;                 // [5000]
  int* cursor = aux + 5000;          // [5000]
  int* start  = aux + 10000;         // [5001]
  int* csr    = aux + 15001;         // [20000]

  const bool big_ws = (ws_size >= H_BYTES + XB_BYTES + AUX_INTS * sizeof(int));

  cvt_kernel<<<(BS * NNODES * CIN) / (256 * 8), 256, 0, stream>>>(x, xb);
  gemm_elu_kernel<<<1264, 256, 0, stream>>>(xb, indices, weight, bias, h);

  if (big_ws) {
    hipMemsetAsync(cnt, 0, 10000 * sizeof(int), stream);   // cnt + cursor
    hist_kernel<<<(NNZ + 255) / 256, 256, 0, stream>>>(trows, cnt);
    scan_kernel<<<1, 256, 0, stream>>>(cnt, start);
    reorder_kernel<<<(NNZ + 255) / 256, 256, 0, stream>>>(trows, start, cursor, csr);
    pool_kernel<<<20000, 256, 0, stream>>>(h, tcols, tvals, start, csr, out);
  } else {
    hipMemsetAsync(d_out, 0, (size_t)out_size * sizeof(float), stream);
    scatter_kernel<<<4096, 256, 0, stream>>>(h, trows, tcols, tvals, out);
  }
}